// Round 8
// baseline (123.485 us; speedup 1.0000x reference)
//
#include <hip/hip_runtime.h>
#include <hip/hip_bf16.h>
#include <math.h>

constexpr int kB = 128;
constexpr int kT = 256;
constexpr int kC = 384;
constexpr int kH = 64;

using bf16x8 = __attribute__((ext_vector_type(8))) short;  // 8 bf16 = 4 VGPRs
using f32x4  = __attribute__((ext_vector_type(4))) float;

union BF8 { bf16x8 v; __hip_bfloat162 h[4]; };
union BF4 { short4 s; __hip_bfloat162 h[2]; };

__device__ inline bf16x8 cvt8(float4 a, float4 b) {
    BF8 u;
    u.h[0] = __float22bfloat162_rn(float2{a.x, a.y});
    u.h[1] = __float22bfloat162_rn(float2{a.z, a.w});
    u.h[2] = __float22bfloat162_rn(float2{b.x, b.y});
    u.h[3] = __float22bfloat162_rn(float2{b.z, b.w});
    return u.v;
}
__device__ inline short4 cvt4(float4 a) {
    BF4 u;
    u.h[0] = __float22bfloat162_rn(float2{a.x, a.y});
    u.h[1] = __float22bfloat162_rn(float2{a.z, a.w});
    return u.s;
}
__device__ inline short bf1(float f) {
    __hip_bfloat16 h = __float2bfloat16(f);
    return *(short*)&h;
}

// ---------------------------------------------------------------------------
// Kernel 0: Wt[n][k] bf16, n in [0,192) = (w*64+h), k in [0,384).
// Wk rows pre-scaled by 384^-0.5 (k only feeds scores).
// ---------------------------------------------------------------------------
__global__ void prep_kernel(const float* __restrict__ Wq,
                            const float* __restrict__ Wk,
                            const float* __restrict__ Wv,
                            __hip_bfloat16* __restrict__ Wt) {
    int idx = blockIdx.x * 256 + threadIdx.x;     // [0, 192*384)
    int n = idx / kC, c = idx % kC;
    int w = n >> 6, h = n & 63;
    const float* W = (w == 0) ? Wq : (w == 1) ? Wk : Wv;
    float val = W[c * kH + h];
    if (w == 1) val *= 0.051031036307982884f;     // 384^-0.5
    Wt[idx] = __float2bfloat16(val);
}

// ---------------------------------------------------------------------------
// Fused kernel. Block = (b, half): t-rows [t0, t0+128), t0 = half*128.
// Phase 1: project x rows [0, t0+128) -> Qs/VTs (and rows >= t0 -> Ks) in LDS
//   via BK=64 double-buffered MFMA GEMM (waves 0-3 stage x, 4-7 stage Wt;
//   all 8 compute 2x3 16x16 tiles). k cols pre-scaled via Wt.
// Phase 2 (ONE barrier after phase 1, then barrier-free): wave w owns t-band
//   [t0+16w, t0+16w+16); loops its s-chunks of 64 reading Qs/VTs/Ks from LDS;
//   online softmax; P round-trip through per-wave slice of the (dead) phase-1
//   staging buffer. Writes fp32 out.
// LDS: Qs 34816 + VTs 33280 + Ks 17408 + STG 73728 = 159232 B (1 block/CU).
// ---------------------------------------------------------------------------
__global__ __launch_bounds__(512, 2) void fused_kernel(
    const float* __restrict__ x, const __hip_bfloat16* __restrict__ Wt,
    float* __restrict__ out)
{
    __shared__ short Qs[256 * 68];                 // [s][h]   stride 68
    __shared__ short VTs[64 * 260];                // [h][s]   stride 260
    __shared__ short Ks[128 * 68];                 // [t-t0][h] stride 68
    __shared__ __attribute__((aligned(16))) char STG[73728];
    short (*As)[64 * 72]  = (short (*)[64 * 72])STG;            // 2 x 9216 B
    short (*Bs)[192 * 72] = (short (*)[192 * 72])(STG + 18432); // 2 x 27648 B

    const int b    = blockIdx.y;
    const int half = (int)blockIdx.x ^ 1;          // heavy half dispatches first
    const int t0   = half * 128;
    const int nmc  = (t0 + 128) >> 6;              // m-chunks: 2 or 4

    const int tid  = threadIdx.x;
    const int wave = tid >> 6, lane = tid & 63;
    const int m16  = lane & 15, quad = lane >> 4;
    const int wm = wave & 1, wn = wave >> 1;
    const short* wt = (const short*)Wt;
    const float* xb = x + (size_t)b * kT * kC;

    // ---------------- Phase 1: projection ----------------
    const bool stageA = (tid < 256);
    const int am  = tid >> 2;                      // A: x row in chunk [0,64)
    const int ak0 = (tid & 3) * 16;                // A: fp32 col chunk
    const int bu  = tid - 256;                     // B: chunk base

    float4 la[4]; bf16x8 lb[6];
    auto glod = [&](int m0, int k0) {
        if (stageA) {
#pragma unroll
            for (int i = 0; i < 4; ++i)
                la[i] = *(const float4*)(xb + (size_t)(m0 + am) * kC + k0 + ak0 + 4 * i);
        } else {
#pragma unroll
            for (int i = 0; i < 6; ++i) {
                int c = bu + 256 * i;              // [0,1536)
                int n = c >> 3, kk = (c & 7) * 8;
                lb[i] = *(const bf16x8*)(wt + (size_t)n * kC + k0 + kk);
            }
        }
    };
    auto swr = [&](int d) {
        if (stageA) {
#pragma unroll
            for (int i = 0; i < 4; ++i)
                *(short4*)&As[d][am * 72 + ak0 + 4 * i] = cvt4(la[i]);
        } else {
#pragma unroll
            for (int i = 0; i < 6; ++i) {
                int c = bu + 256 * i;
                int n = c >> 3, kk = (c & 7) * 8;
                *(bf16x8*)&Bs[d][n * 72 + kk] = lb[i];
            }
        }
    };

    for (int mc = 0; mc < nmc; ++mc) {
        const int m0 = mc * 64;

        f32x4 acc[2][3];
#pragma unroll
        for (int mt = 0; mt < 2; ++mt)
#pragma unroll
            for (int j = 0; j < 3; ++j) acc[mt][j] = f32x4{0.f, 0.f, 0.f, 0.f};

        glod(m0, 0);
        swr(0);
        __syncthreads();

        for (int s = 0; s < 6; ++s) {
            const int d = s & 1;
            if (s < 5) glod(m0, (s + 1) * 64);
#pragma unroll
            for (int kf = 0; kf < 2; ++kf) {
                bf16x8 af[2], bfr[3];
#pragma unroll
                for (int mt = 0; mt < 2; ++mt)
                    af[mt] = *(const bf16x8*)&As[d][(wm * 32 + mt * 16 + m16) * 72 + kf * 32 + quad * 8];
#pragma unroll
                for (int j = 0; j < 3; ++j)
                    bfr[j] = *(const bf16x8*)&Bs[d][(wn * 48 + j * 16 + m16) * 72 + kf * 32 + quad * 8];
#pragma unroll
                for (int mt = 0; mt < 2; ++mt)
#pragma unroll
                    for (int j = 0; j < 3; ++j)
                        acc[mt][j] = __builtin_amdgcn_mfma_f32_16x16x32_bf16(
                            af[mt], bfr[j], acc[mt][j], 0, 0, 0);
            }
            if (s < 5) swr(d ^ 1);
            __syncthreads();
        }

        // epilogue: C-layout (col=m16 in-tile, row=quad*4+r) -> LDS homes
#pragma unroll
        for (int mt = 0; mt < 2; ++mt) {
            const int mbase = m0 + wm * 32 + mt * 16 + quad * 4;
#pragma unroll
            for (int j = 0; j < 3; ++j) {
                const int n = wn * 48 + j * 16 + m16;
                const int w = n >> 6, h = n & 63;
                if (w == 2) {
                    float4 f = make_float4(acc[mt][j][0], acc[mt][j][1],
                                           acc[mt][j][2], acc[mt][j][3]);
                    *(short4*)&VTs[h * 260 + mbase] = cvt4(f);   // s = mbase..+3
                } else if (w == 1) {
                    if (m0 >= t0) {                 // chunk-uniform
#pragma unroll
                        for (int r = 0; r < 4; ++r)
                            Ks[(mbase + r - t0) * 68 + h] = bf1(acc[mt][j][r]);
                    }
                } else {
#pragma unroll
                    for (int r = 0; r < 4; ++r)
                        Qs[(mbase + r) * 68 + h] = bf1(acc[mt][j][r]);
                }
            }
        }
    }
    __syncthreads();   // phase boundary: all of Qs/VTs/Ks visible

    // ---------------- Phase 2: attention (barrier-free) ----------------
    const int wband = t0 + wave * 16;              // this wave's t-band
    float* Pw = (float*)STG + wave * 16 * 68;      // private P scratch

    const bf16x8 ka0 = *(const bf16x8*)&Ks[(wave * 16 + m16) * 68 + quad * 8];
    const bf16x8 ka1 = *(const bf16x8*)&Ks[(wave * 16 + m16) * 68 + quad * 8 + 32];

    f32x4 O[4];
    float m_[4], l_[4];
#pragma unroll
    for (int i = 0; i < 4; ++i) {
        O[i] = f32x4{0.f, 0.f, 0.f, 0.f};
        m_[i] = -INFINITY; l_[i] = 0.f;
    }

    const int ilast = wband >> 6;
    for (int i = 0; i <= ilast; ++i) {
        const bool diag = (i == ilast);
        const int jmax = diag ? (wave & 3) : 3;    // wave-uniform

        f32x4 S[4];
        const f32x4 Z = f32x4{0.f, 0.f, 0.f, 0.f};
#pragma unroll
        for (int j = 0; j < 4; ++j) {
            if (j <= jmax) {
                bf16x8 qb0 = *(const bf16x8*)&Qs[(i * 64 + j * 16 + m16) * 68 + quad * 8];
                bf16x8 qb1 = *(const bf16x8*)&Qs[(i * 64 + j * 16 + m16) * 68 + quad * 8 + 32];
                S[j] = __builtin_amdgcn_mfma_f32_16x16x32_bf16(ka0, qb0, Z, 0, 0, 0);
                S[j] = __builtin_amdgcn_mfma_f32_16x16x32_bf16(ka1, qb1, S[j], 0, 0, 0);
            }
        }
        if (diag) {    // j == jmax tile straddles the diagonal
#pragma unroll
            for (int r = 0; r < 4; ++r)
                if (m16 > quad * 4 + r) S[jmax][r] = -INFINITY;
        }

        float P[4][4];
#pragma unroll
        for (int j = 0; j < 4; ++j)
#pragma unroll
            for (int r = 0; r < 4; ++r) P[j][r] = 0.f;
#pragma unroll
        for (int r = 0; r < 4; ++r) {
            float rm = -INFINITY;
#pragma unroll
            for (int j = 0; j < 4; ++j)
                if (j <= jmax) rm = fmaxf(rm, S[j][r]);
            rm = fmaxf(rm, __shfl_xor(rm, 1, 64));
            rm = fmaxf(rm, __shfl_xor(rm, 2, 64));
            rm = fmaxf(rm, __shfl_xor(rm, 4, 64));
            rm = fmaxf(rm, __shfl_xor(rm, 8, 64));
            const float mn = fmaxf(m_[r], rm);
            const float al = __expf(m_[r] - mn);
            m_[r] = mn;
            float rs = 0.f;
#pragma unroll
            for (int j = 0; j < 4; ++j) {
                if (j <= jmax) { P[j][r] = __expf(S[j][r] - mn); rs += P[j][r]; }
            }
            rs += __shfl_xor(rs, 1, 64);
            rs += __shfl_xor(rs, 2, 64);
            rs += __shfl_xor(rs, 4, 64);
            rs += __shfl_xor(rs, 8, 64);
            l_[r] = l_[r] * al + rs;
            O[0][r] *= al; O[1][r] *= al; O[2][r] *= al; O[3][r] *= al;
        }

        // P: C-layout write (zeros beyond jmax), A-layout read, cvt bf16
#pragma unroll
        for (int j = 0; j < 4; ++j)
#pragma unroll
            for (int r = 0; r < 4; ++r)
                Pw[(quad * 4 + r) * 68 + j * 16 + m16] = P[j][r];
        const float* pr = Pw + m16 * 68 + quad * 8;
        bf16x8 pf0 = cvt8(*(const float4*)pr,        *(const float4*)(pr + 4));
        bf16x8 pf1 = cvt8(*(const float4*)(pr + 32), *(const float4*)(pr + 36));

        // O += P @ V  (V from LDS, [h][s])
#pragma unroll
        for (int ht = 0; ht < 4; ++ht) {
            bf16x8 vb0 = *(const bf16x8*)&VTs[(ht * 16 + m16) * 260 + i * 64 + quad * 8];
            bf16x8 vb1 = *(const bf16x8*)&VTs[(ht * 16 + m16) * 260 + i * 64 + quad * 8 + 32];
            O[ht] = __builtin_amdgcn_mfma_f32_16x16x32_bf16(pf0, vb0, O[ht], 0, 0, 0);
            O[ht] = __builtin_amdgcn_mfma_f32_16x16x32_bf16(pf1, vb1, O[ht], 0, 0, 0);
        }
    }

    // epilogue
#pragma unroll
    for (int r = 0; r < 4; ++r) {
        const float inv = 1.f / l_[r];
        const size_t row = (size_t)(b * kT + wband + quad * 4 + r);
#pragma unroll
        for (int ht = 0; ht < 4; ++ht)
            out[row * kH + ht * 16 + m16] = O[ht][r] * inv;
    }
}

// ---------------------------------------------------------------------------
extern "C" void kernel_launch(void* const* d_in, const int* in_sizes, int n_in,
                              void* d_out, int out_size, void* d_ws, size_t ws_size,
                              hipStream_t stream) {
    const float* x  = (const float*)d_in[0];
    const float* Wq = (const float*)d_in[1];
    const float* Wk = (const float*)d_in[2];
    const float* Wv = (const float*)d_in[3];
    float* out = (float*)d_out;

    __hip_bfloat16* Wt = (__hip_bfloat16*)d_ws;    // 147 KB [n][k]

    prep_kernel<<<(192 * kC) / 256, 256, 0, stream>>>(Wq, Wk, Wv, Wt);
    fused_kernel<<<dim3(2, kB), 512, 0, stream>>>(x, Wt, out);
}

// Round 9
// 118.506 us; speedup vs baseline: 1.0420x; 1.0420x over previous
//
#include <hip/hip_runtime.h>
#include <hip/hip_bf16.h>
#include <math.h>

constexpr int kB = 128;
constexpr int kT = 256;
constexpr int kC = 384;
constexpr int kH = 64;

using bf16x8 = __attribute__((ext_vector_type(8))) short;  // 8 bf16 = 4 VGPRs
using f32x4  = __attribute__((ext_vector_type(4))) float;

union BF8 { bf16x8 v; __hip_bfloat162 h[4]; };
union BF4 { short4 s; __hip_bfloat162 h[2]; };

__device__ inline bf16x8 cvt8(float4 a, float4 b) {
    BF8 u;
    u.h[0] = __float22bfloat162_rn(float2{a.x, a.y});
    u.h[1] = __float22bfloat162_rn(float2{a.z, a.w});
    u.h[2] = __float22bfloat162_rn(float2{b.x, b.y});
    u.h[3] = __float22bfloat162_rn(float2{b.z, b.w});
    return u.v;
}
__device__ inline short4 cvt4(float4 a) {
    BF4 u;
    u.h[0] = __float22bfloat162_rn(float2{a.x, a.y});
    u.h[1] = __float22bfloat162_rn(float2{a.z, a.w});
    return u.s;
}
__device__ inline short bf1(float f) {
    __hip_bfloat16 h = __float2bfloat16(f);
    return *(short*)&h;
}

// ---------------------------------------------------------------------------
// Kernel 0: Wt[n][k] bf16, n in [0,192) = (w*64+h), k in [0,384).
// Wk rows pre-scaled by 384^-0.5 (k only feeds scores).
// ---------------------------------------------------------------------------
__global__ void prep_kernel(const float* __restrict__ Wq,
                            const float* __restrict__ Wk,
                            const float* __restrict__ Wv,
                            __hip_bfloat16* __restrict__ Wt) {
    int idx = blockIdx.x * 256 + threadIdx.x;     // [0, 192*384)
    int n = idx / kC, c = idx % kC;
    int w = n >> 6, h = n & 63;
    const float* W = (w == 0) ? Wq : (w == 1) ? Wk : Wv;
    float val = W[c * kH + h];
    if (w == 1) val *= 0.051031036307982884f;     // 384^-0.5
    Wt[idx] = __float2bfloat16(val);
}

// ---------------------------------------------------------------------------
// Fused kernel. Block = (b, half), 512 threads. Phase 1 is UNIFORM across
// halves: one M=256 x N=192 GEMM pass, BK=32, 12 double-buffered K-steps
// (Wt staged exactly once; no m-chunk loop). Wave (wm=wave&1, wn=wave>>1)
// owns 8 m-tiles x 3 n-tiles = 24 MFMA/step, acc 96 VGPR. Epilogue scatters
// C-layout into Qs[s][h] / Ks[t-t0][h] / VTs[h][s] (strides 72/72/264 shorts,
// all == 4 mod 32 dwords: the round-6/7 conflict-free class).
// Phase 2 (one barrier, then barrier-free): wave owns t-band
// [t0+16*wave, +16); flash attention read entirely from LDS; P round-trip
// through the dead As staging buffer (stride 68 floats).
// LDS total: 36864+18432+33792+40960+30720 = 160768 B (1 block/CU).
// ---------------------------------------------------------------------------
__global__ __launch_bounds__(512, 2) void fused_kernel(
    const float* __restrict__ x, const __hip_bfloat16* __restrict__ Wt,
    float* __restrict__ out)
{
    __shared__ short Qs[256 * 72];      // [s][h]
    __shared__ short Ks[128 * 72];      // [t-t0][h]
    __shared__ short VTs[64 * 264];     // [h][s]
    __shared__ short As[2][256 * 40];   // x tile bf16 [m][kk]
    __shared__ short Bs[2][192 * 40];   // Wt tile    [n][kk]

    const int b    = blockIdx.y;
    const int half = (int)blockIdx.x ^ 1;          // heavy half dispatches first
    const int t0   = half * 128;

    const int tid  = threadIdx.x;
    const int wave = tid >> 6, lane = tid & 63;
    const int m16  = lane & 15, quad = lane >> 4;
    const int wm = wave & 1, wn = wave >> 1;       // m-half, 3-n-tile slice
    const short* wt = (const short*)Wt;
    const float* xb = x + (size_t)b * kT * kC;

    // ---------------- Phase 1: projection (uniform) ----------------
    // A staging: lane covers row tid>>1, 16-col fp32 chunk (tid&1)*16.
    // B staging: chunk c -> n = c>>2, kk = (c&3)*8; lanes cover c = tid and
    // (tid<256) c = tid+512.
    const int arow = tid >> 1, acol = (tid & 1) * 16;

    float4 la[4]; bf16x8 lb0, lb1;
    auto glod = [&](int k0) {
#pragma unroll
        for (int i = 0; i < 4; ++i)
            la[i] = *(const float4*)(xb + (size_t)arow * kC + k0 + acol + 4 * i);
        {
            int n = tid >> 2, kk = (tid & 3) * 8;
            lb0 = *(const bf16x8*)(wt + (size_t)n * kC + k0 + kk);
        }
        if (tid < 256) {
            int c = tid + 512;
            int n = c >> 2, kk = (c & 3) * 8;
            lb1 = *(const bf16x8*)(wt + (size_t)n * kC + k0 + kk);
        }
    };
    auto swr = [&](int d) {
#pragma unroll
        for (int i = 0; i < 4; ++i)
            *(short4*)&As[d][arow * 40 + acol + 4 * i] = cvt4(la[i]);
        {
            int n = tid >> 2, kk = (tid & 3) * 8;
            *(bf16x8*)&Bs[d][n * 40 + kk] = lb0;
        }
        if (tid < 256) {
            int c = tid + 512;
            int n = c >> 2, kk = (c & 3) * 8;
            *(bf16x8*)&Bs[d][n * 40 + kk] = lb1;
        }
    };

    f32x4 acc[8][3];
#pragma unroll
    for (int mt = 0; mt < 8; ++mt)
#pragma unroll
        for (int j = 0; j < 3; ++j) acc[mt][j] = f32x4{0.f, 0.f, 0.f, 0.f};

    glod(0);
    swr(0);
    __syncthreads();

    for (int s = 0; s < 12; ++s) {
        const int d = s & 1;
        if (s < 11) glod((s + 1) * 32);            // next tile in flight

        bf16x8 af[8], bfr[3];
#pragma unroll
        for (int j = 0; j < 3; ++j)
            bfr[j] = *(const bf16x8*)&Bs[d][((wn * 3 + j) * 16 + m16) * 40 + quad * 8];
#pragma unroll
        for (int mt = 0; mt < 8; ++mt)
            af[mt] = *(const bf16x8*)&As[d][(wm * 128 + mt * 16 + m16) * 40 + quad * 8];
#pragma unroll
        for (int mt = 0; mt < 8; ++mt)
#pragma unroll
            for (int j = 0; j < 3; ++j)
                acc[mt][j] = __builtin_amdgcn_mfma_f32_16x16x32_bf16(
                    af[mt], bfr[j], acc[mt][j], 0, 0, 0);

        if (s < 11) swr(d ^ 1);
        __syncthreads();
    }

    // epilogue: C-layout (col = m16 in-tile, rows = quad*4+r) -> LDS homes
#pragma unroll
    for (int mt = 0; mt < 8; ++mt) {
        const int mbase = wm * 128 + mt * 16 + quad * 4;
#pragma unroll
        for (int j = 0; j < 3; ++j) {
            const int nt = wn * 3 + j;             // n-tile 0..11
            const int w  = nt >> 2;                // 0=q, 1=k, 2=v
            const int h  = (nt & 3) * 16 + m16;
            if (w == 2) {
                float4 f = make_float4(acc[mt][j][0], acc[mt][j][1],
                                       acc[mt][j][2], acc[mt][j][3]);
                *(short4*)&VTs[h * 264 + mbase] = cvt4(f);   // s = mbase..+3
            } else if (w == 1) {
                if ((mbase >> 7) == half) {        // rows [t0, t0+128)
#pragma unroll
                    for (int r = 0; r < 4; ++r)
                        Ks[(mbase + r - t0) * 72 + h] = bf1(acc[mt][j][r]);
                }
            } else {
#pragma unroll
                for (int r = 0; r < 4; ++r)
                    Qs[(mbase + r) * 72 + h] = bf1(acc[mt][j][r]);
            }
        }
    }
    __syncthreads();   // phase boundary: Qs/Ks/VTs all visible

    // ---------------- Phase 2: attention (barrier-free) ----------------
    const int wband = t0 + wave * 16;              // this wave's t-band
    float* Pw = (float*)(&As[0][0]) + wave * 16 * 68;  // dead staging buffer

    const bf16x8 ka0 = *(const bf16x8*)&Ks[(wave * 16 + m16) * 72 + quad * 8];
    const bf16x8 ka1 = *(const bf16x8*)&Ks[(wave * 16 + m16) * 72 + quad * 8 + 32];

    f32x4 O[4];
    float m_[4], l_[4];
#pragma unroll
    for (int i = 0; i < 4; ++i) {
        O[i] = f32x4{0.f, 0.f, 0.f, 0.f};
        m_[i] = -INFINITY; l_[i] = 0.f;
    }

    const int ilast = wband >> 6;
    for (int i = 0; i <= ilast; ++i) {
        const bool diag = (i == ilast);
        const int jmax = diag ? (wave & 3) : 3;    // wave-uniform

        f32x4 S[4];
        const f32x4 Z = f32x4{0.f, 0.f, 0.f, 0.f};
#pragma unroll
        for (int j = 0; j < 4; ++j) {
            if (j <= jmax) {
                bf16x8 qb0 = *(const bf16x8*)&Qs[(i * 64 + j * 16 + m16) * 72 + quad * 8];
                bf16x8 qb1 = *(const bf16x8*)&Qs[(i * 64 + j * 16 + m16) * 72 + quad * 8 + 32];
                S[j] = __builtin_amdgcn_mfma_f32_16x16x32_bf16(ka0, qb0, Z, 0, 0, 0);
                S[j] = __builtin_amdgcn_mfma_f32_16x16x32_bf16(ka1, qb1, S[j], 0, 0, 0);
            }
        }
        if (diag) {    // j == jmax tile straddles the diagonal
#pragma unroll
            for (int r = 0; r < 4; ++r)
                if (m16 > quad * 4 + r) S[jmax][r] = -INFINITY;
        }

        float P[4][4];
#pragma unroll
        for (int j = 0; j < 4; ++j)
#pragma unroll
            for (int r = 0; r < 4; ++r) P[j][r] = 0.f;
#pragma unroll
        for (int r = 0; r < 4; ++r) {
            float rm = -INFINITY;
#pragma unroll
            for (int j = 0; j < 4; ++j)
                if (j <= jmax) rm = fmaxf(rm, S[j][r]);
            rm = fmaxf(rm, __shfl_xor(rm, 1, 64));
            rm = fmaxf(rm, __shfl_xor(rm, 2, 64));
            rm = fmaxf(rm, __shfl_xor(rm, 4, 64));
            rm = fmaxf(rm, __shfl_xor(rm, 8, 64));
            const float mn = fmaxf(m_[r], rm);
            const float al = __expf(m_[r] - mn);
            m_[r] = mn;
            float rs = 0.f;
#pragma unroll
            for (int j = 0; j < 4; ++j) {
                if (j <= jmax) { P[j][r] = __expf(S[j][r] - mn); rs += P[j][r]; }
            }
            rs += __shfl_xor(rs, 1, 64);
            rs += __shfl_xor(rs, 2, 64);
            rs += __shfl_xor(rs, 4, 64);
            rs += __shfl_xor(rs, 8, 64);
            l_[r] = l_[r] * al + rs;
            O[0][r] *= al; O[1][r] *= al; O[2][r] *= al; O[3][r] *= al;
        }

        // P: C-layout write (zeros beyond jmax), A-layout read, cvt bf16
#pragma unroll
        for (int j = 0; j < 4; ++j)
#pragma unroll
            for (int r = 0; r < 4; ++r)
                Pw[(quad * 4 + r) * 68 + j * 16 + m16] = P[j][r];
        const float* pr = Pw + m16 * 68 + quad * 8;
        bf16x8 pf0 = cvt8(*(const float4*)pr,        *(const float4*)(pr + 4));
        bf16x8 pf1 = cvt8(*(const float4*)(pr + 32), *(const float4*)(pr + 36));

        // O += P @ V  (V from LDS, [h][s])
#pragma unroll
        for (int ht = 0; ht < 4; ++ht) {
            bf16x8 vb0 = *(const bf16x8*)&VTs[(ht * 16 + m16) * 264 + i * 64 + quad * 8];
            bf16x8 vb1 = *(const bf16x8*)&VTs[(ht * 16 + m16) * 264 + i * 64 + quad * 8 + 32];
            O[ht] = __builtin_amdgcn_mfma_f32_16x16x32_bf16(pf0, vb0, O[ht], 0, 0, 0);
            O[ht] = __builtin_amdgcn_mfma_f32_16x16x32_bf16(pf1, vb1, O[ht], 0, 0, 0);
        }
    }

    // epilogue
#pragma unroll
    for (int r = 0; r < 4; ++r) {
        const float inv = 1.f / l_[r];
        const size_t row = (size_t)(b * kT + wband + quad * 4 + r);
#pragma unroll
        for (int ht = 0; ht < 4; ++ht)
            out[row * kH + ht * 16 + m16] = O[ht][r] * inv;
    }
}

// ---------------------------------------------------------------------------
extern "C" void kernel_launch(void* const* d_in, const int* in_sizes, int n_in,
                              void* d_out, int out_size, void* d_ws, size_t ws_size,
                              hipStream_t stream) {
    const float* x  = (const float*)d_in[0];
    const float* Wq = (const float*)d_in[1];
    const float* Wk = (const float*)d_in[2];
    const float* Wv = (const float*)d_in[3];
    float* out = (float*)d_out;

    __hip_bfloat16* Wt = (__hip_bfloat16*)d_ws;    // 147 KB [n][k]

    prep_kernel<<<(192 * kC) / 256, 256, 0, stream>>>(Wq, Wk, Wv, Wt);
    fused_kernel<<<dim3(2, kB), 512, 0, stream>>>(x, Wt, out);
}

// Round 10
// 116.432 us; speedup vs baseline: 1.0606x; 1.0178x over previous
//
#include <hip/hip_runtime.h>
#include <hip/hip_bf16.h>
#include <math.h>

constexpr int kB = 128;
constexpr int kT = 256;
constexpr int kC = 384;
constexpr int kH = 64;

using bf16x8 = __attribute__((ext_vector_type(8))) short;  // 8 bf16 = 4 VGPRs
using f32x4  = __attribute__((ext_vector_type(4))) float;

union BF8 { bf16x8 v; __hip_bfloat162 h[4]; };
union BF4 { short4 s; __hip_bfloat162 h[2]; };

__device__ inline bf16x8 cvt8(float4 a, float4 b) {
    BF8 u;
    u.h[0] = __float22bfloat162_rn(float2{a.x, a.y});
    u.h[1] = __float22bfloat162_rn(float2{a.z, a.w});
    u.h[2] = __float22bfloat162_rn(float2{b.x, b.y});
    u.h[3] = __float22bfloat162_rn(float2{b.z, b.w});
    return u.v;
}
__device__ inline short4 cvt4(float4 a) {
    BF4 u;
    u.h[0] = __float22bfloat162_rn(float2{a.x, a.y});
    u.h[1] = __float22bfloat162_rn(float2{a.z, a.w});
    return u.s;
}
__device__ inline short bf1(float f) {
    __hip_bfloat16 h = __float2bfloat16(f);
    return *(short*)&h;
}

// ---------------------------------------------------------------------------
// Kernel 0: Wt[n][k] bf16, n in [0,192) = (w*64+h), k in [0,384).
// Wk rows pre-scaled by 384^-0.5 (k only feeds scores).
// ---------------------------------------------------------------------------
__global__ void prep_kernel(const float* __restrict__ Wq,
                            const float* __restrict__ Wk,
                            const float* __restrict__ Wv,
                            __hip_bfloat16* __restrict__ Wt) {
    int idx = blockIdx.x * 256 + threadIdx.x;     // [0, 192*384)
    int n = idx / kC, c = idx % kC;
    int w = n >> 6, h = n & 63;
    const float* W = (w == 0) ? Wq : (w == 1) ? Wk : Wv;
    float val = W[c * kH + h];
    if (w == 1) val *= 0.051031036307982884f;     // 384^-0.5
    Wt[idx] = __float2bfloat16(val);
}

// ---------------------------------------------------------------------------
// Fused kernel. Block = (b, half), 512 threads. Phase 1: one M x 192 GEMM
// pass (M = 256 heavy half / 128 light half via wave-uniform masking), BK=32,
// 12 double-buffered K-steps, Wt staged exactly once. Staging strides 36
// shorts (18 dwords): 18*m16 mod 32 covers all even banks once -> staging
// writes <=2-way (free), b128 frag reads in the round-7-verified free class.
// Epilogue scatters C-layout into Qs[s][h]/Ks[t-t0][h]/VTs[h][s] (72/72/264).
// Phase 2 (one barrier, then barrier-free): wave owns t-band [t0+16w,+16);
// flash attention entirely from LDS; P via dead As buffer (stride 68 floats).
// LDS: 36864(Qs)+18432(Ks)+33792(VTs)+36864(As)+27648(Bs)=153600 B, 1 blk/CU.
// ---------------------------------------------------------------------------
__global__ __launch_bounds__(512, 2) void fused_kernel(
    const float* __restrict__ x, const __hip_bfloat16* __restrict__ Wt,
    float* __restrict__ out)
{
    __shared__ short Qs[256 * 72];      // [s][h]
    __shared__ short Ks[128 * 72];      // [t-t0][h]
    __shared__ short VTs[64 * 264];     // [h][s]
    __shared__ short As[2][256 * 36];   // x tile bf16 [m][kk], stride 36
    __shared__ short Bs[2][192 * 36];   // Wt tile    [n][kk], stride 36

    const int b    = blockIdx.y;
    const int half = (int)blockIdx.x ^ 1;          // heavy half dispatches first
    const int t0   = half * 128;

    const int tid  = threadIdx.x;
    const int wave = tid >> 6, lane = tid & 63;
    const int m16  = lane & 15, quad = lane >> 4;
    const int wm = wave & 1, wn = wave >> 1;       // m-half, 3-n-tile slice
    const short* wt = (const short*)Wt;
    const float* xb = x + (size_t)b * kT * kC;

    // wave-uniform activity masks for the light half (M = 128)
    const bool mfmaAct = (half == 1) || (wm == 0);

    // ---------------- Phase 1: projection ----------------
    // A staging: row = tid>>1 (waves 0-3 -> rows 0-127, 4-7 -> 128-255, so
    // the light-half skip is wave-uniform), 16-col fp32 chunk (tid&1)*16.
    const int arow = tid >> 1, acol = (tid & 1) * 16;
    const bool aAct = (half == 1) || (arow < 128);

    float4 la[4]; bf16x8 lb0, lb1;
    auto glod = [&](int k0) {
        if (aAct) {
#pragma unroll
            for (int i = 0; i < 4; ++i)
                la[i] = *(const float4*)(xb + (size_t)arow * kC + k0 + acol + 4 * i);
        }
        {
            int n = tid >> 2, kk = (tid & 3) * 8;
            lb0 = *(const bf16x8*)(wt + (size_t)n * kC + k0 + kk);
        }
        if (tid < 256) {
            int c = tid + 512;
            int n = c >> 2, kk = (c & 3) * 8;
            lb1 = *(const bf16x8*)(wt + (size_t)n * kC + k0 + kk);
        }
    };
    auto swr = [&](int d) {
        if (aAct) {
#pragma unroll
            for (int i = 0; i < 4; ++i)
                *(short4*)&As[d][arow * 36 + acol + 4 * i] = cvt4(la[i]);
        }
        {
            int n = tid >> 2, kk = (tid & 3) * 8;
            *(bf16x8*)&Bs[d][n * 36 + kk] = lb0;
        }
        if (tid < 256) {
            int c = tid + 512;
            int n = c >> 2, kk = (c & 3) * 8;
            *(bf16x8*)&Bs[d][n * 36 + kk] = lb1;
        }
    };

    f32x4 acc[8][3];
#pragma unroll
    for (int mt = 0; mt < 8; ++mt)
#pragma unroll
        for (int j = 0; j < 3; ++j) acc[mt][j] = f32x4{0.f, 0.f, 0.f, 0.f};

    glod(0);
    swr(0);
    __syncthreads();

    for (int s = 0; s < 12; ++s) {
        const int d = s & 1;
        if (s < 11) glod((s + 1) * 32);            // next tile in flight

        if (mfmaAct) {
            bf16x8 af[8], bfr[3];
#pragma unroll
            for (int j = 0; j < 3; ++j)
                bfr[j] = *(const bf16x8*)&Bs[d][((wn * 3 + j) * 16 + m16) * 36 + quad * 8];
#pragma unroll
            for (int mt = 0; mt < 8; ++mt)
                af[mt] = *(const bf16x8*)&As[d][(wm * 128 + mt * 16 + m16) * 36 + quad * 8];
#pragma unroll
            for (int mt = 0; mt < 8; ++mt)
#pragma unroll
                for (int j = 0; j < 3; ++j)
                    acc[mt][j] = __builtin_amdgcn_mfma_f32_16x16x32_bf16(
                        af[mt], bfr[j], acc[mt][j], 0, 0, 0);
        }

        if (s < 11) swr(d ^ 1);
        __syncthreads();
    }

    // epilogue: C-layout (col = m16 in-tile, rows = quad*4+r) -> LDS homes
    if (mfmaAct) {
#pragma unroll
        for (int mt = 0; mt < 8; ++mt) {
            const int mbase = wm * 128 + mt * 16 + quad * 4;
#pragma unroll
            for (int j = 0; j < 3; ++j) {
                const int nt = wn * 3 + j;             // n-tile 0..11
                const int w  = nt >> 2;                // 0=q, 1=k, 2=v
                const int h  = (nt & 3) * 16 + m16;
                if (w == 2) {
                    float4 f = make_float4(acc[mt][j][0], acc[mt][j][1],
                                           acc[mt][j][2], acc[mt][j][3]);
                    *(short4*)&VTs[h * 264 + mbase] = cvt4(f);   // s = mbase..+3
                } else if (w == 1) {
                    if ((mbase >> 7) == half) {        // rows [t0, t0+128)
#pragma unroll
                        for (int r = 0; r < 4; ++r)
                            Ks[(mbase + r - t0) * 72 + h] = bf1(acc[mt][j][r]);
                    }
                } else {
#pragma unroll
                    for (int r = 0; r < 4; ++r)
                        Qs[(mbase + r) * 72 + h] = bf1(acc[mt][j][r]);
                }
            }
        }
    }
    __syncthreads();   // phase boundary: Qs/Ks/VTs all visible

    // ---------------- Phase 2: attention (barrier-free) ----------------
    const int wband = t0 + wave * 16;              // this wave's t-band
    float* Pw = (float*)(&As[0][0]) + wave * 16 * 68;  // dead staging buffer

    const bf16x8 ka0 = *(const bf16x8*)&Ks[(wave * 16 + m16) * 72 + quad * 8];
    const bf16x8 ka1 = *(const bf16x8*)&Ks[(wave * 16 + m16) * 72 + quad * 8 + 32];

    f32x4 O[4];
    float m_[4], l_[4];
#pragma unroll
    for (int i = 0; i < 4; ++i) {
        O[i] = f32x4{0.f, 0.f, 0.f, 0.f};
        m_[i] = -INFINITY; l_[i] = 0.f;
    }

    const int ilast = wband >> 6;
    for (int i = 0; i <= ilast; ++i) {
        const bool diag = (i == ilast);
        const int jmax = diag ? (wave & 3) : 3;    // wave-uniform

        f32x4 S[4];
        const f32x4 Z = f32x4{0.f, 0.f, 0.f, 0.f};
#pragma unroll
        for (int j = 0; j < 4; ++j) {
            if (j <= jmax) {
                bf16x8 qb0 = *(const bf16x8*)&Qs[(i * 64 + j * 16 + m16) * 72 + quad * 8];
                bf16x8 qb1 = *(const bf16x8*)&Qs[(i * 64 + j * 16 + m16) * 72 + quad * 8 + 32];
                S[j] = __builtin_amdgcn_mfma_f32_16x16x32_bf16(ka0, qb0, Z, 0, 0, 0);
                S[j] = __builtin_amdgcn_mfma_f32_16x16x32_bf16(ka1, qb1, S[j], 0, 0, 0);
            }
        }
        if (diag) {    // j == jmax tile straddles the diagonal
#pragma unroll
            for (int r = 0; r < 4; ++r)
                if (m16 > quad * 4 + r) S[jmax][r] = -INFINITY;
        }

        float P[4][4];
#pragma unroll
        for (int j = 0; j < 4; ++j)
#pragma unroll
            for (int r = 0; r < 4; ++r) P[j][r] = 0.f;
#pragma unroll
        for (int r = 0; r < 4; ++r) {
            float rm = -INFINITY;
#pragma unroll
            for (int j = 0; j < 4; ++j)
                if (j <= jmax) rm = fmaxf(rm, S[j][r]);
            rm = fmaxf(rm, __shfl_xor(rm, 1, 64));
            rm = fmaxf(rm, __shfl_xor(rm, 2, 64));
            rm = fmaxf(rm, __shfl_xor(rm, 4, 64));
            rm = fmaxf(rm, __shfl_xor(rm, 8, 64));
            const float mn = fmaxf(m_[r], rm);
            const float al = __expf(m_[r] - mn);
            m_[r] = mn;
            float rs = 0.f;
#pragma unroll
            for (int j = 0; j < 4; ++j) {
                if (j <= jmax) { P[j][r] = __expf(S[j][r] - mn); rs += P[j][r]; }
            }
            rs += __shfl_xor(rs, 1, 64);
            rs += __shfl_xor(rs, 2, 64);
            rs += __shfl_xor(rs, 4, 64);
            rs += __shfl_xor(rs, 8, 64);
            l_[r] = l_[r] * al + rs;
            O[0][r] *= al; O[1][r] *= al; O[2][r] *= al; O[3][r] *= al;
        }

        // P: C-layout write (zeros beyond jmax), A-layout read, cvt bf16
#pragma unroll
        for (int j = 0; j < 4; ++j)
#pragma unroll
            for (int r = 0; r < 4; ++r)
                Pw[(quad * 4 + r) * 68 + j * 16 + m16] = P[j][r];
        const float* pr = Pw + m16 * 68 + quad * 8;
        bf16x8 pf0 = cvt8(*(const float4*)pr,        *(const float4*)(pr + 4));
        bf16x8 pf1 = cvt8(*(const float4*)(pr + 32), *(const float4*)(pr + 36));

        // O += P @ V  (V from LDS, [h][s])
#pragma unroll
        for (int ht = 0; ht < 4; ++ht) {
            bf16x8 vb0 = *(const bf16x8*)&VTs[(ht * 16 + m16) * 264 + i * 64 + quad * 8];
            bf16x8 vb1 = *(const bf16x8*)&VTs[(ht * 16 + m16) * 264 + i * 64 + quad * 8 + 32];
            O[ht] = __builtin_amdgcn_mfma_f32_16x16x32_bf16(pf0, vb0, O[ht], 0, 0, 0);
            O[ht] = __builtin_amdgcn_mfma_f32_16x16x32_bf16(pf1, vb1, O[ht], 0, 0, 0);
        }
    }

    // epilogue
#pragma unroll
    for (int r = 0; r < 4; ++r) {
        const float inv = 1.f / l_[r];
        const size_t row = (size_t)(b * kT + wband + quad * 4 + r);
#pragma unroll
        for (int ht = 0; ht < 4; ++ht)
            out[row * kH + ht * 16 + m16] = O[ht][r] * inv;
    }
}

// ---------------------------------------------------------------------------
extern "C" void kernel_launch(void* const* d_in, const int* in_sizes, int n_in,
                              void* d_out, int out_size, void* d_ws, size_t ws_size,
                              hipStream_t stream) {
    const float* x  = (const float*)d_in[0];
    const float* Wq = (const float*)d_in[1];
    const float* Wk = (const float*)d_in[2];
    const float* Wv = (const float*)d_in[3];
    float* out = (float*)d_out;

    __hip_bfloat16* Wt = (__hip_bfloat16*)d_ws;    // 147 KB [n][k]

    prep_kernel<<<(192 * kC) / 256, 256, 0, stream>>>(Wq, Wk, Wv, Wt);
    fused_kernel<<<dim3(2, kB), 512, 0, stream>>>(x, Wt, out);
}